// Round 1
// baseline (873.234 us; speedup 1.0000x reference)
//
#include <hip/hip_runtime.h>
#include <stdint.h>

typedef unsigned int uint;
typedef unsigned short ushort;
typedef __attribute__((ext_vector_type(4))) float f32x4;
typedef __attribute__((ext_vector_type(8))) short short8;
typedef __attribute__((ext_vector_type(2))) uint uint2v;
typedef __attribute__((ext_vector_type(4))) uint uint4v;

#define GLOBAL_AS __attribute__((address_space(1)))
#define LDS_AS __attribute__((address_space(3)))

static constexpr int B_ = 2048, IN_ = 4096, OUT_ = 4096;
static constexpr int NT = 32;  // K chunks of 128 (crossbar tiles)

static constexpr double kGRangeD = 1e-4 - 1e-5;
static constexpr float kGMin  = 1e-5f;
static constexpr float kGMax  = 1e-4f;
static constexpr float kGRange = (float)kGRangeD;            // 9e-5
static constexpr float kD2D   = (float)(0.01 * kGRangeD);    // D2D_STD
static constexpr float kRead  = (float)(0.02 * kGRangeD);    // READ_NOISE_STD
static constexpr float kInvGR = (float)(1.0 / kGRangeD);     // decode scale

// ---------------- init: zero the scalar slots (max_x, tile_max[32]) --------
__global__ void k_init(uint* scal) {
    if (threadIdx.x < 64) scal[threadIdx.x] = 0u;
}

// ---------------- global max|x| -------------------------------------------
__global__ void k_maxabs(const f32x4* __restrict__ x, int n4, uint* __restrict__ scal) {
    int stride = gridDim.x * blockDim.x;
    float m = 0.f;
    for (int i = blockIdx.x * blockDim.x + threadIdx.x; i < n4; i += stride) {
        f32x4 v = x[i];
        m = fmaxf(m, fmaxf(fmaxf(fabsf(v[0]), fabsf(v[1])), fmaxf(fabsf(v[2]), fabsf(v[3]))));
    }
#pragma unroll
    for (int off = 32; off; off >>= 1) m = fmaxf(m, __shfl_xor(m, off, 64));
    if ((threadIdx.x & 63) == 0) atomicMax(scal, __float_as_uint(m));
}

// ---------------- DAC quantize x -> integer codes stored as bf16 ----------
// k = clip(rint(x/step), -127, 127); codes are exact in bf16.
__global__ void k_quantx(const f32x4* __restrict__ x, uint4v* __restrict__ xq, int n8,
                         const uint* __restrict__ scal) {
    float mx = __uint_as_float(scal[0]);
    float s = mx / 127.0f;  // matches ref step exactly (f32 division)
    int stride = gridDim.x * blockDim.x;
    for (int i = blockIdx.x * blockDim.x + threadIdx.x; i < n8; i += stride) {
        f32x4 a = x[2 * i], b = x[2 * i + 1];
        uint r[8];
#pragma unroll
        for (int j = 0; j < 4; ++j) {
            float q0 = fminf(fmaxf(rintf(a[j] / s), -127.f), 127.f);
            float q1 = fminf(fmaxf(rintf(b[j] / s), -127.f), 127.f);
            r[j]     = __float_as_uint(q0) >> 16;  // exact: small ints fit bf16
            r[4 + j] = __float_as_uint(q1) >> 16;
        }
        uint4v o;
        o[0] = r[0] | (r[1] << 16); o[1] = r[2] | (r[3] << 16);
        o[2] = r[4] | (r[5] << 16); o[3] = r[6] | (r[7] << 16);
        xq[i] = o;
    }
}

// ---------------- effective weight (decode-folded) -> bf16 ----------------
__global__ void k_weff(const f32x4* __restrict__ W, const f32x4* __restrict__ dp,
                       const f32x4* __restrict__ dn, const f32x4* __restrict__ npz,
                       const f32x4* __restrict__ nnz, uint2v* __restrict__ wb, int n4) {
    int stride = gridDim.x * blockDim.x;
    for (int i = blockIdx.x * blockDim.x + threadIdx.x; i < n4; i += stride) {
        f32x4 w = W[i], a = dp[i], b = dn[i], c = npz[i], d = nnz[i];
        uint h[4];
#pragma unroll
        for (int j = 0; j < 4; ++j) {
            float wc = fminf(fmaxf(w[j], -1.f), 1.f);
            float gp = kGMin + fmaxf(wc, 0.f) * kGRange;
            float gn = kGMin + fmaxf(-wc, 0.f) * kGRange;
            gp = fminf(fmaxf(gp + kD2D * a[j] + kRead * c[j], 0.f), kGMax);
            gn = fminf(fmaxf(gn + kD2D * b[j] + kRead * d[j], 0.f), kGMax);
            float wv = (gp - gn) * kInvGR;
            uint u = __float_as_uint(wv);
            h[j] = (u + 0x7FFFu + ((u >> 16) & 1u)) >> 16;  // RNE to bf16
        }
        uint2v o; o[0] = h[0] | (h[1] << 16); o[1] = h[2] | (h[3] << 16);
        wb[i] = o;
    }
}

// ---------------- two-pass tiled GEMM with per-chunk ADC ------------------
// PASS 1: compute per-chunk partials, atomicMax the 32 chunk maxima.
// PASS 2: recompute (bitwise identical), quantize with maxima, accumulate,
//         write out = acc * step_x + bias.
template <int PASS>
__global__ __launch_bounds__(256, 2) void k_gemm(const ushort* __restrict__ A,
                                                 const ushort* __restrict__ Bw,
                                                 uint* __restrict__ scal,
                                                 const float* __restrict__ bias,
                                                 float* __restrict__ out) {
    constexpr int K = IN_;
    __shared__ ushort At[128 * 32];
    __shared__ ushort Bt[128 * 32];

    const int tid = threadIdx.x;
    const int lane = tid & 63;
    const int wave = tid >> 6;
    const int wr = wave >> 1, wc = wave & 1;
    const int lr = lane & 15, half = lane >> 4;
    const int bm = blockIdx.x & 15, bn = blockIdx.x >> 4;
    const int brow = bm * 128, bcol = bn * 128;

    // staging: 512 16B segments per tile; thread handles seg tid and tid+256
    const ushort* ga = A + (size_t)(brow + (tid >> 2)) * K + (tid & 3) * 8;
    const ushort* gb = Bw + (size_t)(bcol + (tid >> 2)) * K + (tid & 3) * 8;

    const int aoff = (wr * 64 + lr) * 32 + half * 8;
    const int boff = (wc * 64 + lr) * 32 + half * 8;

    f32x4 acc_o[4][4];
    if (PASS == 2) {
#pragma unroll
        for (int mi = 0; mi < 4; ++mi)
#pragma unroll
            for (int ni = 0; ni < 4; ++ni) acc_o[mi][ni] = f32x4{0.f, 0.f, 0.f, 0.f};
    }

    for (int t = 0; t < NT; ++t) {
        f32x4 acc[4][4];
#pragma unroll
        for (int mi = 0; mi < 4; ++mi)
#pragma unroll
            for (int ni = 0; ni < 4; ++ni) acc[mi][ni] = f32x4{0.f, 0.f, 0.f, 0.f};

#pragma unroll
        for (int s = 0; s < 4; ++s) {
            const int k0 = t * 128 + s * 32;
            __builtin_amdgcn_global_load_lds((const GLOBAL_AS uint*)(ga + k0),
                                             (LDS_AS uint*)&At[tid * 8], 16, 0, 0);
            __builtin_amdgcn_global_load_lds((const GLOBAL_AS uint*)(ga + (size_t)64 * K + k0),
                                             (LDS_AS uint*)&At[(tid + 256) * 8], 16, 0, 0);
            __builtin_amdgcn_global_load_lds((const GLOBAL_AS uint*)(gb + k0),
                                             (LDS_AS uint*)&Bt[tid * 8], 16, 0, 0);
            __builtin_amdgcn_global_load_lds((const GLOBAL_AS uint*)(gb + (size_t)64 * K + k0),
                                             (LDS_AS uint*)&Bt[(tid + 256) * 8], 16, 0, 0);
            __syncthreads();
            short8 af[4], bfr[4];
#pragma unroll
            for (int mi = 0; mi < 4; ++mi) af[mi] = *(const short8*)&At[aoff + mi * 16 * 32];
#pragma unroll
            for (int ni = 0; ni < 4; ++ni) bfr[ni] = *(const short8*)&Bt[boff + ni * 16 * 32];
#pragma unroll
            for (int mi = 0; mi < 4; ++mi)
#pragma unroll
                for (int ni = 0; ni < 4; ++ni)
                    acc[mi][ni] = __builtin_amdgcn_mfma_f32_16x16x32_bf16(af[mi], bfr[ni],
                                                                          acc[mi][ni], 0, 0, 0);
            __syncthreads();
        }

        if (PASS == 1) {
            float m = 0.f;
#pragma unroll
            for (int mi = 0; mi < 4; ++mi)
#pragma unroll
                for (int ni = 0; ni < 4; ++ni) {
                    f32x4 v = acc[mi][ni];
                    m = fmaxf(m, fmaxf(fmaxf(fabsf(v[0]), fabsf(v[1])),
                                       fmaxf(fabsf(v[2]), fabsf(v[3]))));
                }
#pragma unroll
            for (int off = 32; off; off >>= 1) m = fmaxf(m, __shfl_xor(m, off, 64));
            if (lane == 0) atomicMax(&scal[1 + t], __float_as_uint(m));
        } else {
            float mt = __uint_as_float(scal[1 + t]);
            float stp = mt / 127.0f;
            float inv = mt > 0.f ? 127.0f / mt : 0.f;
#pragma unroll
            for (int mi = 0; mi < 4; ++mi)
#pragma unroll
                for (int ni = 0; ni < 4; ++ni)
#pragma unroll
                    for (int e = 0; e < 4; ++e)
                        acc_o[mi][ni][e] = fmaf(rintf(acc[mi][ni][e] * inv), stp, acc_o[mi][ni][e]);
        }
    }

    if (PASS == 2) {
        float sx = __uint_as_float(scal[0]) / 127.0f;
#pragma unroll
        for (int mi = 0; mi < 4; ++mi)
#pragma unroll
            for (int ni = 0; ni < 4; ++ni) {
                int gr = brow + wr * 64 + mi * 16 + half * 4;
                int gc = bcol + wc * 64 + ni * 16 + lr;
                float bv = bias[gc];
#pragma unroll
                for (int e = 0; e < 4; ++e)
                    out[(size_t)(gr + e) * OUT_ + gc] = fmaf(acc_o[mi][ni][e], sx, bv);
            }
    }
}

extern "C" void kernel_launch(void* const* d_in, const int* in_sizes, int n_in,
                              void* d_out, int out_size, void* d_ws, size_t ws_size,
                              hipStream_t stream) {
    (void)in_sizes; (void)n_in; (void)out_size;
    const float* x   = (const float*)d_in[0];
    const float* W   = (const float*)d_in[1];
    const float* bias= (const float*)d_in[2];
    const float* dp  = (const float*)d_in[3];
    const float* dn  = (const float*)d_in[4];
    const float* npz = (const float*)d_in[5];
    const float* nnz = (const float*)d_in[6];
    float* out = (float*)d_out;

    uint* scal = (uint*)d_ws;
    ushort* xq = (ushort*)((char*)d_ws + 256);
    ushort* wb = (ushort*)((char*)d_ws + 256 + (size_t)B_ * IN_ * 2);
    if (ws_size < 256 + (size_t)B_ * IN_ * 2 + (size_t)OUT_ * IN_ * 2) return;

    k_init<<<1, 64, 0, stream>>>(scal);
    k_maxabs<<<2048, 256, 0, stream>>>((const f32x4*)x, B_ * IN_ / 4, scal);
    k_quantx<<<2048, 256, 0, stream>>>((const f32x4*)x, (uint4v*)xq, B_ * IN_ / 8, scal);
    k_weff<<<2048, 256, 0, stream>>>((const f32x4*)W, (const f32x4*)dp, (const f32x4*)dn,
                                     (const f32x4*)npz, (const f32x4*)nnz,
                                     (uint2v*)wb, OUT_ * IN_ / 4);
    k_gemm<1><<<512, 256, 0, stream>>>(xq, wb, scal, bias, out);
    k_gemm<2><<<512, 256, 0, stream>>>(xq, wb, scal, bias, out);
}

// Round 2
// 391.645 us; speedup vs baseline: 2.2297x; 2.2297x over previous
//
#include <hip/hip_runtime.h>
#include <stdint.h>

typedef unsigned int uint;
typedef unsigned short ushort;
typedef __attribute__((ext_vector_type(4))) float f32x4;
typedef __attribute__((ext_vector_type(8))) short short8;
typedef __attribute__((ext_vector_type(2))) uint uint2v;
typedef __attribute__((ext_vector_type(4))) uint uint4v;

#define GLOBAL_AS __attribute__((address_space(1)))
#define LDS_AS __attribute__((address_space(3)))

static constexpr int B_ = 2048, IN_ = 4096, OUT_ = 4096;
static constexpr int NT = 32;   // K chunks of 128 (crossbar tiles)
static constexpr int K = IN_;

static constexpr double kGRangeD = 1e-4 - 1e-5;
static constexpr float kGMin  = 1e-5f;
static constexpr float kGMax  = 1e-4f;
static constexpr float kGRange = (float)kGRangeD;            // 9e-5
static constexpr float kD2D   = (float)(0.01 * kGRangeD);    // D2D_STD
static constexpr float kRead  = (float)(0.02 * kGRangeD);    // READ_NOISE_STD
static constexpr float kInvGR = (float)(1.0 / kGRangeD);     // decode scale

// ---------------- init: zero the scalar slots (max_x, tile_max[32]) --------
__global__ void k_init(uint* scal) {
    if (threadIdx.x < 64) scal[threadIdx.x] = 0u;
}

// ---------------- global max|x| -------------------------------------------
__global__ void k_maxabs(const f32x4* __restrict__ x, int n4, uint* __restrict__ scal) {
    int stride = gridDim.x * blockDim.x;
    float m = 0.f;
    for (int i = blockIdx.x * blockDim.x + threadIdx.x; i < n4; i += stride) {
        f32x4 v = x[i];
        m = fmaxf(m, fmaxf(fmaxf(fabsf(v[0]), fabsf(v[1])), fmaxf(fabsf(v[2]), fabsf(v[3]))));
    }
#pragma unroll
    for (int off = 32; off; off >>= 1) m = fmaxf(m, __shfl_xor(m, off, 64));
    if ((threadIdx.x & 63) == 0) atomicMax(scal, __float_as_uint(m));
}

// ---------------- DAC quantize x -> integer codes stored as bf16 ----------
__global__ void k_quantx(const f32x4* __restrict__ x, uint4v* __restrict__ xq, int n8,
                         const uint* __restrict__ scal) {
    float mx = __uint_as_float(scal[0]);
    float s = mx / 127.0f;
    int stride = gridDim.x * blockDim.x;
    for (int i = blockIdx.x * blockDim.x + threadIdx.x; i < n8; i += stride) {
        f32x4 a = x[2 * i], b = x[2 * i + 1];
        uint r[8];
#pragma unroll
        for (int j = 0; j < 4; ++j) {
            float q0 = fminf(fmaxf(rintf(a[j] / s), -127.f), 127.f);
            float q1 = fminf(fmaxf(rintf(b[j] / s), -127.f), 127.f);
            r[j]     = __float_as_uint(q0) >> 16;  // exact: small ints fit bf16
            r[4 + j] = __float_as_uint(q1) >> 16;
        }
        uint4v o;
        o[0] = r[0] | (r[1] << 16); o[1] = r[2] | (r[3] << 16);
        o[2] = r[4] | (r[5] << 16); o[3] = r[6] | (r[7] << 16);
        xq[i] = o;
    }
}

// ---------------- effective weight (decode-folded) -> bf16 ----------------
__global__ void k_weff(const f32x4* __restrict__ W, const f32x4* __restrict__ dp,
                       const f32x4* __restrict__ dn, const f32x4* __restrict__ npz,
                       const f32x4* __restrict__ nnz, uint2v* __restrict__ wb, int n4) {
    int stride = gridDim.x * blockDim.x;
    for (int i = blockIdx.x * blockDim.x + threadIdx.x; i < n4; i += stride) {
        f32x4 w = W[i], a = dp[i], b = dn[i], c = npz[i], d = nnz[i];
        uint h[4];
#pragma unroll
        for (int j = 0; j < 4; ++j) {
            float wc = fminf(fmaxf(w[j], -1.f), 1.f);
            float gp = kGMin + fmaxf(wc, 0.f) * kGRange;
            float gn = kGMin + fmaxf(-wc, 0.f) * kGRange;
            gp = fminf(fmaxf(gp + kD2D * a[j] + kRead * c[j], 0.f), kGMax);
            gn = fminf(fmaxf(gn + kD2D * b[j] + kRead * d[j], 0.f), kGMax);
            float wv = (gp - gn) * kInvGR;
            uint u = __float_as_uint(wv);
            h[j] = (u + 0x7FFFu + ((u >> 16) & 1u)) >> 16;  // RNE to bf16
        }
        uint2v o; o[0] = h[0] | (h[1] << 16); o[1] = h[2] | (h[3] << 16);
        wb[i] = o;
    }
}

// ---------------- two-pass tiled GEMM with per-chunk ADC ------------------
// 128x128 tile, BK=64, double-buffered LDS, stage-before-compute 2-phase.
// LDS layout [128][64] ushort with seg' = seg ^ (row&7) XOR swizzle applied
// on the GLOBAL source (gload_lds dest must be linear) and on the ds_read.
template <int PASS>
__global__ __launch_bounds__(256, 2) void k_gemm(const ushort* __restrict__ A,
                                                 const ushort* __restrict__ Bw,
                                                 uint* __restrict__ scal,
                                                 const float* __restrict__ bias,
                                                 float* __restrict__ out) {
    __shared__ ushort As[2][128 * 64];
    __shared__ ushort Bs[2][128 * 64];
    __shared__ uint cmax[NT];

    const int tid = threadIdx.x;
    const int lane = tid & 63;
    const int wave = tid >> 6;
    const int wr = wave >> 1, wc = wave & 1;
    const int lr = lane & 15, half = lane >> 4;
    const int bm = blockIdx.x & 15, bn = blockIdx.x >> 4;
    const int brow = bm * 128, bcol = bn * 128;

    if (PASS == 1 && tid < NT) cmax[tid] = 0u;

    // staging geometry: thread -> (row = tid>>3, seg = tid&7), 16B per thread,
    // 4 insts per matrix (rows += 32). Source col pre-XOR'd by row&7.
    const int srow = tid >> 3;
    const int sxor = ((tid & 7) ^ (srow & 7)) * 8;
    const ushort* gaA = A  + (size_t)(brow + srow) * K + sxor;
    const ushort* gaB = Bw + (size_t)(bcol + srow) * K + sxor;
    const int ldst = tid * 8;  // ushort offset of this thread's 16B slot

#define STAGE(buf, k0)                                                                   \
    do {                                                                                 \
        _Pragma("unroll")                                                                \
        for (int inst = 0; inst < 4; ++inst) {                                           \
            __builtin_amdgcn_global_load_lds(                                            \
                (const GLOBAL_AS uint*)(gaA + (size_t)inst * 32 * K + (k0)),             \
                (LDS_AS uint*)&As[buf][inst * 2048 + ldst], 16, 0, 0);                   \
            __builtin_amdgcn_global_load_lds(                                            \
                (const GLOBAL_AS uint*)(gaB + (size_t)inst * 32 * K + (k0)),             \
                (LDS_AS uint*)&Bs[buf][inst * 2048 + ldst], 16, 0, 0);                   \
        }                                                                                \
    } while (0)

    // fragment read offsets (ushort units). row*64 + (seg ^ (lr&7))*8
    int rowA[4], rowB[4];
#pragma unroll
    for (int i = 0; i < 4; ++i) {
        rowA[i] = (wr * 64 + lr + i * 16) * 64;
        rowB[i] = (wc * 64 + lr + i * 16) * 64;
    }
    const int lx = lr & 7;

    f32x4 acc[4][4];
    f32x4 acc_o[4][4];
#pragma unroll
    for (int mi = 0; mi < 4; ++mi)
#pragma unroll
        for (int ni = 0; ni < 4; ++ni) {
            acc[mi][ni] = f32x4{0.f, 0.f, 0.f, 0.f};
            acc_o[mi][ni] = f32x4{0.f, 0.f, 0.f, 0.f};
        }

#define COMPUTE(buf)                                                                     \
    do {                                                                                 \
        _Pragma("unroll")                                                                \
        for (int s2 = 0; s2 < 2; ++s2) {                                                 \
            const int sx = ((s2 * 4 + half) ^ lx) * 8;                                   \
            short8 af[4], bf[4];                                                         \
            _Pragma("unroll")                                                            \
            for (int mi = 0; mi < 4; ++mi) af[mi] = *(const short8*)&As[buf][rowA[mi] + sx]; \
            _Pragma("unroll")                                                            \
            for (int ni = 0; ni < 4; ++ni) bf[ni] = *(const short8*)&Bs[buf][rowB[ni] + sx]; \
            _Pragma("unroll")                                                            \
            for (int mi = 0; mi < 4; ++mi)                                               \
                _Pragma("unroll")                                                        \
                for (int ni = 0; ni < 4; ++ni)                                           \
                    acc[mi][ni] = __builtin_amdgcn_mfma_f32_16x16x32_bf16(               \
                        af[mi], bf[ni], acc[mi][ni], 0, 0, 0);                           \
        }                                                                                \
    } while (0)

    // prologue: stage step 0 into buf 0
    STAGE(0, 0);
    __syncthreads();

    for (int t = 0; t < NT; ++t) {
        // even step 2t (buf 0): stage next, compute current
        STAGE(1, (2 * t + 1) * 64);
        COMPUTE(0);
        __syncthreads();
        // odd step 2t+1 (buf 1)
        if (t < NT - 1) STAGE(0, (2 * t + 2) * 64);
        COMPUTE(1);

        // ---- ADC for chunk t ----
        if (PASS == 1) {
            float m = 0.f;
#pragma unroll
            for (int mi = 0; mi < 4; ++mi)
#pragma unroll
                for (int ni = 0; ni < 4; ++ni) {
                    f32x4 v = acc[mi][ni];
                    m = fmaxf(m, fmaxf(fmaxf(fabsf(v[0]), fabsf(v[1])),
                                       fmaxf(fabsf(v[2]), fabsf(v[3]))));
                }
#pragma unroll
            for (int off = 32; off; off >>= 1) m = fmaxf(m, __shfl_xor(m, off, 64));
            if (lane == 0) atomicMax(&cmax[t], __float_as_uint(m));
        } else {
            float mt = __uint_as_float(scal[1 + t]);
            float stp = mt / 127.0f;
            float inv = mt > 0.f ? 127.0f / mt : 0.f;
#pragma unroll
            for (int mi = 0; mi < 4; ++mi)
#pragma unroll
                for (int ni = 0; ni < 4; ++ni)
#pragma unroll
                    for (int e = 0; e < 4; ++e)
                        acc_o[mi][ni][e] = fmaf(rintf(acc[mi][ni][e] * inv), stp, acc_o[mi][ni][e]);
        }
        // reset chunk accumulator
#pragma unroll
        for (int mi = 0; mi < 4; ++mi)
#pragma unroll
            for (int ni = 0; ni < 4; ++ni) acc[mi][ni] = f32x4{0.f, 0.f, 0.f, 0.f};

        __syncthreads();
    }

    if (PASS == 1) {
        __syncthreads();
        if (tid < NT) atomicMax(&scal[1 + tid], cmax[tid]);
    } else {
        float sxq = __uint_as_float(scal[0]) / 127.0f;
#pragma unroll
        for (int mi = 0; mi < 4; ++mi)
#pragma unroll
            for (int ni = 0; ni < 4; ++ni) {
                int gr = brow + wr * 64 + mi * 16 + half * 4;
                int gc = bcol + wc * 64 + ni * 16 + lr;
                float bv = bias[gc];
#pragma unroll
                for (int e = 0; e < 4; ++e)
                    out[(size_t)(gr + e) * OUT_ + gc] = fmaf(acc_o[mi][ni][e], sxq, bv);
            }
    }
#undef STAGE
#undef COMPUTE
}

extern "C" void kernel_launch(void* const* d_in, const int* in_sizes, int n_in,
                              void* d_out, int out_size, void* d_ws, size_t ws_size,
                              hipStream_t stream) {
    (void)in_sizes; (void)n_in; (void)out_size;
    const float* x   = (const float*)d_in[0];
    const float* W   = (const float*)d_in[1];
    const float* bias= (const float*)d_in[2];
    const float* dp  = (const float*)d_in[3];
    const float* dn  = (const float*)d_in[4];
    const float* npz = (const float*)d_in[5];
    const float* nnz = (const float*)d_in[6];
    float* out = (float*)d_out;

    uint* scal = (uint*)d_ws;
    ushort* xq = (ushort*)((char*)d_ws + 256);
    ushort* wb = (ushort*)((char*)d_ws + 256 + (size_t)B_ * IN_ * 2);
    if (ws_size < 256 + (size_t)B_ * IN_ * 2 + (size_t)OUT_ * IN_ * 2) return;

    k_init<<<1, 64, 0, stream>>>(scal);
    k_maxabs<<<2048, 256, 0, stream>>>((const f32x4*)x, B_ * IN_ / 4, scal);
    k_quantx<<<2048, 256, 0, stream>>>((const f32x4*)x, (uint4v*)xq, B_ * IN_ / 8, scal);
    k_weff<<<2048, 256, 0, stream>>>((const f32x4*)W, (const f32x4*)dp, (const f32x4*)dn,
                                     (const f32x4*)npz, (const f32x4*)nnz,
                                     (uint2v*)wb, OUT_ * IN_ / 4);
    k_gemm<1><<<512, 256, 0, stream>>>(xq, wb, scal, bias, out);
    k_gemm<2><<<512, 256, 0, stream>>>(xq, wb, scal, bias, out);
}